// Round 2
// baseline (496.208 us; speedup 1.0000x reference)
//
#include <hip/hip_runtime.h>

typedef short short8 __attribute__((ext_vector_type(8)));
typedef short short4v __attribute__((ext_vector_type(4)));
typedef float f32x4 __attribute__((ext_vector_type(4)));
typedef __bf16 bf16x8 __attribute__((ext_vector_type(8)));
typedef _Float16 half4 __attribute__((ext_vector_type(4)));

__device__ __forceinline__ short f2bf(float x) {
  unsigned u = __builtin_bit_cast(unsigned, x);
  u += 0x7fffu + ((u >> 16) & 1u);   // round-to-nearest-even
  return (short)(u >> 16);
}

__device__ __forceinline__ f32x4 mfma16(short8 a, short8 b, f32x4 c) {
  return __builtin_amdgcn_mfma_f32_16x16x32_bf16(
      __builtin_bit_cast(bf16x8, a), __builtin_bit_cast(bf16x8, b), c, 0, 0, 0);
}

// ---------------- conversion kernels ----------------

__global__ __launch_bounds__(256) void cvt_bf16_kernel(
    const float* __restrict__ x, short* __restrict__ y, int n) {
  int i = blockIdx.x * 256 + threadIdx.x;
  if (i < n) y[i] = f2bf(x[i]);
}

// W: [K][N] f32 row-major  ->  BT: [N][K] bf16 row-major
__global__ __launch_bounds__(256) void transpose_cvt_kernel(
    const float* __restrict__ W, short* __restrict__ BT, int K, int N) {
  __shared__ short tile[32][33];
  int bn = blockIdx.x * 32, bk = blockIdx.y * 32;
  int tx = threadIdx.x, ty = threadIdx.y;  // 32 x 8
  for (int i = ty; i < 32; i += 8)
    tile[i][tx] = f2bf(W[(size_t)(bk + i) * N + bn + tx]);
  __syncthreads();
  for (int i = ty; i < 32; i += 8)
    BT[(size_t)(bn + i) * K + bk + tx] = tile[tx][i];
}

// ---------------- GEMM: C[M,N] = A[M,K] @ BT[N,K]^T ----------------

template <int EPI>
__global__ __launch_bounds__(256) void gemm_bt_kernel(
    const short* __restrict__ A, const short* __restrict__ BT,
    int M, int N, int K, float* __restrict__ C,
    const float* __restrict__ bias, const float* __restrict__ resid,
    float* __restrict__ out) {
  int tid = threadIdx.x;
  int l = tid & 63, w = tid >> 6;
  int wr = w >> 1, wc = w & 1;
  int lr = l & 15, lg = l >> 4;
  int bm = blockIdx.y * 64, bn = blockIdx.x * 64;
  f32x4 acc[2][2] = {};
  const short* arow = A + (size_t)(bm + wr * 32 + lr) * K + lg * 8;
  const short* brow = BT + (size_t)(bn + wc * 32 + lr) * K + lg * 8;
  for (int k0 = 0; k0 < K; k0 += 32) {
    short8 a0 = *(const short8*)(arow + k0);
    short8 a1 = *(const short8*)(arow + (size_t)16 * K + k0);
    short8 b0 = *(const short8*)(brow + k0);
    short8 b1 = *(const short8*)(brow + (size_t)16 * K + k0);
    acc[0][0] = mfma16(a0, b0, acc[0][0]);
    acc[0][1] = mfma16(a0, b1, acc[0][1]);
    acc[1][0] = mfma16(a1, b0, acc[1][0]);
    acc[1][1] = mfma16(a1, b1, acc[1][1]);
  }
#pragma unroll
  for (int mi = 0; mi < 2; mi++)
#pragma unroll
    for (int ni = 0; ni < 2; ni++)
#pragma unroll
      for (int i = 0; i < 4; i++) {
        int row = bm + wr * 32 + mi * 16 + lg * 4 + i;
        int col = bn + wc * 32 + ni * 16 + lr;
        float v = acc[mi][ni][i];
        if (EPI == 1)
          out[(size_t)row * N + col] = v + bias[col] + resid[(size_t)row * N + col];
        else
          C[(size_t)row * N + col] = v;
      }
}

// ---------------- CAPE + head split ----------------
// qkv: [2048][3840] f32. qb,kb: [20][2048][64] bf16 ; vt: [20][64][2048] f16
// q is pre-scaled by hd^-0.5 * log2(e) so attention works in exp2 domain.
__global__ __launch_bounds__(256) void cape_split_kernel(
    const float* __restrict__ qkv, const float* __restrict__ p_out,
    const float* __restrict__ p_inv, short* __restrict__ qb,
    short* __restrict__ kb, _Float16* __restrict__ vt) {
  int idx = blockIdx.x * 256 + threadIdx.x;  // s*320 + g, grid is exact
  int s = idx / 320;
  int g = idx - s * 320;
  int t = s >> 10;
  const float* Pq = p_inv + t * 16;   // q uses p_out_inv
  const float* Pk = p_out + t * 16;   // k uses p_out
  const float* row = qkv + (size_t)s * 3840 + g * 4;
  float qv[4], kv[4], vv[4];
#pragma unroll
  for (int i = 0; i < 4; i++) {
    qv[i] = row[i];
    kv[i] = row[1280 + i];
    vv[i] = row[2560 + i];
  }
  int h = g >> 4;
  int dvb = (g & 15) * 4;
  const float QSCALE = 0.125f * 1.44269504f;  // hd^-0.5 * log2(e)
  short4v qo, ko;
#pragma unroll
  for (int j = 0; j < 4; j++) {
    float aq = 0.f, ak = 0.f;
#pragma unroll
    for (int k2 = 0; k2 < 4; k2++) {
      aq += qv[k2] * Pq[k2 * 4 + j];
      ak += kv[k2] * Pk[k2 * 4 + j];
    }
    qo[j] = f2bf(aq * QSCALE);
    ko[j] = f2bf(ak);
  }
  size_t base = ((size_t)h * 2048 + s) * 64 + dvb;
  *(short4v*)(qb + base) = qo;
  *(short4v*)(kb + base) = ko;
#pragma unroll
  for (int j = 0; j < 4; j++)
    vt[((size_t)h * 64 + dvb + j) * 2048 + s] = (_Float16)vv[j];
}

// ---------------- flash attention (no LDS, register-resident P) ----------------
// qb,kb: [20][2048][64] bf16, vt: [20][64][2048] f16, attn_out bf16 [2048][1280]
__global__ __launch_bounds__(256) void attn_kernel(
    const short* __restrict__ qb, const short* __restrict__ kb,
    const _Float16* __restrict__ vt, short* __restrict__ attn_out) {
  const int S = 2048, HD = 64;
  int h = blockIdx.x;
  int qblk = blockIdx.y;
  int tid = threadIdx.x;
  int w = tid >> 6, l = tid & 63;
  int lr = l & 15, lg = l >> 4;
  int q0 = qblk * 64 + w * 16;

  // Q fragment (B operand of S^T mfma): lane holds Q[q0+lr][lg*8+j] per 32-d half
  const short* qptr = qb + ((size_t)h * S + q0 + lr) * HD;
  short8 qf0 = *(const short8*)(qptr + lg * 8);
  short8 qf1 = *(const short8*)(qptr + 32 + lg * 8);

  const short* kbase = kb + (size_t)h * S * HD + lr * HD + lg * 8;
  const _Float16* vbase = vt + ((size_t)h * HD + lr) * S + lg * 4;

  float m = -1e30f, lsum = 0.f;
  f32x4 oacc[4] = {};  // O[q=lg*4+i][dv=nb*16+lr]

  // preload K tile 0: kf[kk][half], rows kt*64 + kk*16 + lr
  short8 kf[4][2];
#pragma unroll
  for (int kk = 0; kk < 4; kk++) {
    const short* kp = kbase + (size_t)(kk * 16) * HD;
    kf[kk][0] = *(const short8*)(kp);
    kf[kk][1] = *(const short8*)(kp + 32);
  }

  for (int kt = 0; kt < 32; ++kt) {
    // ---- QK^T: st[kk] holds S[key=kk*16+lg*4+i][q=lr] (already log2-scaled) ----
    f32x4 st[4];
#pragma unroll
    for (int kk = 0; kk < 4; kk++) {
      f32x4 s0 = {};
      s0 = mfma16(kf[kk][0], qf0, s0);
      s0 = mfma16(kf[kk][1], qf1, s0);
      st[kk] = s0;
    }
    // ---- V loads for this tile (B operand, K=16 f16 PV) ----
    half4 vf[4][4];
#pragma unroll
    for (int kk = 0; kk < 4; kk++)
#pragma unroll
      for (int nb = 0; nb < 4; nb++)
        vf[kk][nb] = *(const half4*)(vbase + (size_t)(nb * 16) * S + kt * 64 + kk * 16);
    // ---- prefetch next K tile (stays in flight across PV: vmcnt) ----
    if (kt + 1 < 32) {
#pragma unroll
      for (int kk = 0; kk < 4; kk++) {
        const short* kp = kbase + (size_t)((kt + 1) * 64 + kk * 16) * HD;
        kf[kk][0] = *(const short8*)(kp);
        kf[kk][1] = *(const short8*)(kp + 32);
      }
    }
    // ---- online softmax in exp2 domain ----
    float m0 = fmaxf(fmaxf(st[0][0], st[0][1]), fmaxf(st[0][2], st[0][3]));
    float m1 = fmaxf(fmaxf(st[1][0], st[1][1]), fmaxf(st[1][2], st[1][3]));
    float m2 = fmaxf(fmaxf(st[2][0], st[2][1]), fmaxf(st[2][2], st[2][3]));
    float m3 = fmaxf(fmaxf(st[3][0], st[3][1]), fmaxf(st[3][2], st[3][3]));
    float tm = fmaxf(fmaxf(m0, m1), fmaxf(m2, m3));
    tm = fmaxf(tm, __shfl_xor(tm, 16));
    tm = fmaxf(tm, __shfl_xor(tm, 32));
    // defer-rescale: only pay the O-rescale when the running max grows by >8
    if (!__all(tm <= m + 8.0f)) {
      float mnew = fmaxf(m, tm);
      float fac = __builtin_amdgcn_exp2f(m - mnew);
      lsum *= fac;
#pragma unroll
      for (int i = 0; i < 4; i++) {
        float fi = __shfl(fac, lg * 4 + i);
#pragma unroll
        for (int nb = 0; nb < 4; nb++) oacc[nb][i] *= fi;
      }
      m = mnew;
    }
    half4 pf[4];
    float ps[4];
#pragma unroll
    for (int kk = 0; kk < 4; kk++) {
      float p0 = __builtin_amdgcn_exp2f(st[kk][0] - m);
      float p1 = __builtin_amdgcn_exp2f(st[kk][1] - m);
      float p2 = __builtin_amdgcn_exp2f(st[kk][2] - m);
      float p3 = __builtin_amdgcn_exp2f(st[kk][3] - m);
      pf[kk][0] = (_Float16)p0;
      pf[kk][1] = (_Float16)p1;
      pf[kk][2] = (_Float16)p2;
      pf[kk][3] = (_Float16)p3;
      ps[kk] = (p0 + p1) + (p2 + p3);
    }
    float psum = (ps[0] + ps[1]) + (ps[2] + ps[3]);
    psum += __shfl_xor(psum, 16);
    psum += __shfl_xor(psum, 32);
    lsum += psum;
    // ---- PV: O[q][dv] += P[q][key] V[key][dv], K=16 f16 MFMA, P from regs ----
#pragma unroll
    for (int kk = 0; kk < 4; kk++)
#pragma unroll
      for (int nb = 0; nb < 4; nb++)
        oacc[nb] = __builtin_amdgcn_mfma_f32_16x16x16f16(pf[kk], vf[kk][nb], oacc[nb], 0, 0, 0);
  }
  // normalize + store: lane holds O[q=lg*4+i][dv=nb*16+lr]
#pragma unroll
  for (int i = 0; i < 4; i++) {
    float li = __shfl(lsum, lg * 4 + i);
    float inv = 1.0f / li;
    int row = q0 + lg * 4 + i;
#pragma unroll
    for (int nb = 0; nb < 4; nb++)
      attn_out[(size_t)row * 1280 + h * 64 + nb * 16 + lr] = f2bf(oacc[nb][i] * inv);
  }
}

// ---------------- launch ----------------

extern "C" void kernel_launch(void* const* d_in, const int* in_sizes, int n_in,
                              void* d_out, int out_size, void* d_ws, size_t ws_size,
                              hipStream_t stream) {
  const float* hs = (const float*)d_in[0];
  const float* p_out = (const float*)d_in[1];
  const float* p_inv = (const float*)d_in[2];
  const float* Wq = (const float*)d_in[3];
  const float* Wk = (const float*)d_in[4];
  const float* Wv = (const float*)d_in[5];
  const float* Wo = (const float*)d_in[6];
  const float* bo = (const float*)d_in[7];
  float* out = (float*)d_out;
  char* ws = (char*)d_ws;

  // workspace layout (all offsets 256B-aligned)
  short* hs_bf = (short*)(ws + 0);              // 2048*1280*2   = 5,242,880
  short* wqkv_t = (short*)(ws + 5242880);       // 3840*1280*2   = 9,830,400
  short* wo_t = (short*)(ws + 15073280);        // 1280*1280*2   = 3,276,800
  float* qkv = (float*)(ws + 18350080);         // 2048*3840*4   = 31,457,280
  short* q_bf = (short*)(ws + 49807360);        // 20*2048*64*2  = 5,242,880
  short* k_bf = (short*)(ws + 55050240);        // 5,242,880
  _Float16* v_t = (_Float16*)(ws + 60293120);   // 5,242,880  (ends 65,536,000)
  short* attn_bf = (short*)(ws + 18350080);     // reuse qkv region after cape_split

  const int n_hs = 2048 * 1280;
  cvt_bf16_kernel<<<(n_hs + 255) / 256, 256, 0, stream>>>(hs, hs_bf, n_hs);

  dim3 tb(32, 8);
  transpose_cvt_kernel<<<dim3(40, 40), tb, 0, stream>>>(Wq, wqkv_t, 1280, 1280);
  transpose_cvt_kernel<<<dim3(40, 40), tb, 0, stream>>>(Wk, wqkv_t + (size_t)1280 * 1280, 1280, 1280);
  transpose_cvt_kernel<<<dim3(40, 40), tb, 0, stream>>>(Wv, wqkv_t + (size_t)2560 * 1280, 1280, 1280);
  transpose_cvt_kernel<<<dim3(40, 40), tb, 0, stream>>>(Wo, wo_t, 1280, 1280);

  // QKV: [2048][1280] @ [1280][3840] -> [2048][3840] f32
  gemm_bt_kernel<0><<<dim3(60, 32), 256, 0, stream>>>(
      hs_bf, wqkv_t, 2048, 3840, 1280, qkv, nullptr, nullptr, nullptr);

  cape_split_kernel<<<2560, 256, 0, stream>>>(qkv, p_out, p_inv, q_bf, k_bf, v_t);

  attn_kernel<<<dim3(20, 32), 256, 0, stream>>>(q_bf, k_bf, v_t, attn_bf);

  // out = attn @ Wo + bo + residual
  gemm_bt_kernel<1><<<dim3(20, 32), 256, 0, stream>>>(
      attn_bf, wo_t, 2048, 1280, 1280, nullptr, bo, hs, out);
}

// Round 3
// 152.908 us; speedup vs baseline: 3.2451x; 3.2451x over previous
//
#include <hip/hip_runtime.h>

typedef short short8 __attribute__((ext_vector_type(8)));
typedef short short4v __attribute__((ext_vector_type(4)));
typedef float f32x4 __attribute__((ext_vector_type(4)));
typedef float float4v __attribute__((ext_vector_type(4)));
typedef __bf16 bf16x8 __attribute__((ext_vector_type(8)));
typedef _Float16 half4 __attribute__((ext_vector_type(4)));

__device__ __forceinline__ short f2bf(float x) {
  unsigned u = __builtin_bit_cast(unsigned, x);
  u += 0x7fffu + ((u >> 16) & 1u);   // round-to-nearest-even
  return (short)(u >> 16);
}

__device__ __forceinline__ f32x4 mfma16(short8 a, short8 b, f32x4 c) {
  return __builtin_amdgcn_mfma_f32_16x16x32_bf16(
      __builtin_bit_cast(bf16x8, a), __builtin_bit_cast(bf16x8, b), c, 0, 0, 0);
}

// async global->LDS, 16B per lane; lds must be wave-uniform base (lane i writes base+i*16)
__device__ __forceinline__ void async16(void* lds, const void* g) {
  __builtin_amdgcn_global_load_lds(
      (const __attribute__((address_space(1))) unsigned*)g,
      (__attribute__((address_space(3))) unsigned*)lds, 16, 0, 0);
}

// ---------------- conversion kernels ----------------

__global__ __launch_bounds__(256) void cvt_bf16_kernel(
    const float* __restrict__ x, short* __restrict__ y, int n) {
  int i = blockIdx.x * 256 + threadIdx.x;
  if (i < n) y[i] = f2bf(x[i]);
}

// W: [K][N] f32 row-major  ->  BT: [N][K] bf16 row-major
__global__ __launch_bounds__(256) void transpose_cvt_kernel(
    const float* __restrict__ W, short* __restrict__ BT, int K, int N) {
  __shared__ short tile[32][33];
  int bn = blockIdx.x * 32, bk = blockIdx.y * 32;
  int tx = threadIdx.x, ty = threadIdx.y;  // 32 x 8
  for (int i = ty; i < 32; i += 8)
    tile[i][tx] = f2bf(W[(size_t)(bk + i) * N + bn + tx]);
  __syncthreads();
  for (int i = ty; i < 32; i += 8)
    BT[(size_t)(bn + i) * K + bk + tx] = tile[tx][i];
}

// ---------------- GEMM (m97 structure): C[M,N] = A[M,K] @ BT[N,K]^T ----------
// 128x128 tile, BK=32, double-buffered LDS via global_load_lds.
// EPI=0: store f32 C. EPI=1: out = acc + bias[col] + resid.

template <int EPI>
__global__ __launch_bounds__(256) void gemm128_kernel(
    const short* __restrict__ A, const short* __restrict__ BT,
    int M, int N, int K, float* __restrict__ C,
    const float* __restrict__ bias, const float* __restrict__ resid,
    float* __restrict__ out) {
  __shared__ __align__(16) short As[2][128][32];
  __shared__ __align__(16) short Bs[2][128][32];
  int tid = threadIdx.x;
  int l = tid & 63, w = tid >> 6;
  int wr = w >> 1, wc = w & 1;
  int lr = l & 15, lg = l >> 4;
  int bm = blockIdx.y * 128, bn = blockIdx.x * 128;
  f32x4 acc[4][4] = {};

  auto stage = [&](int b, int k0) {
    const short* ga = A + (size_t)(bm + (tid >> 2)) * K + k0 + (tid & 3) * 8;
    const short* gb = BT + (size_t)(bn + (tid >> 2)) * K + k0 + (tid & 3) * 8;
    char* la = (char*)&As[b][0][0] + w * 1024;
    char* lb = (char*)&Bs[b][0][0] + w * 1024;
    async16(la, ga);
    async16(la + 4096, ga + (size_t)64 * K);
    async16(lb, gb);
    async16(lb + 4096, gb + (size_t)64 * K);
  };

  auto compute = [&](int b) {
    const short* Ab = &As[b][0][0];
    const short* Bb = &Bs[b][0][0];
    short8 af[4], bf_[4];
#pragma unroll
    for (int mi = 0; mi < 4; mi++)
      af[mi] = *(const short8*)(Ab + (wr * 64 + mi * 16 + lr) * 32 + lg * 8);
#pragma unroll
    for (int nj = 0; nj < 4; nj++)
      bf_[nj] = *(const short8*)(Bb + (wc * 64 + nj * 16 + lr) * 32 + lg * 8);
#pragma unroll
    for (int mi = 0; mi < 4; mi++)
#pragma unroll
      for (int nj = 0; nj < 4; nj++)
        acc[mi][nj] = mfma16(af[mi], bf_[nj], acc[mi][nj]);
  };

  int nk = K >> 5;
  stage(0, 0);
  for (int ks = 0; ks < nk; ks += 2) {
    __syncthreads();
    if (ks + 1 < nk) stage(1, (ks + 1) << 5);
    compute(0);
    __syncthreads();
    if (ks + 2 < nk) stage(0, (ks + 2) << 5);
    compute(1);
  }

#pragma unroll
  for (int mi = 0; mi < 4; mi++)
#pragma unroll
    for (int nj = 0; nj < 4; nj++)
#pragma unroll
      for (int i = 0; i < 4; i++) {
        int row = bm + wr * 64 + mi * 16 + lg * 4 + i;
        int col = bn + wc * 64 + nj * 16 + lr;
        float v = acc[mi][nj][i];
        if (EPI == 1)
          out[(size_t)row * N + col] = v + bias[col] + resid[(size_t)row * N + col];
        else
          C[(size_t)row * N + col] = v;
      }
}

// ---------------- CAPE + head split ----------------
// qkv: [2048][3840] f32.
// qb: [20][2048][64] bf16 (q pre-scaled by hd^-0.5*log2e)
// k_tiled: [20][32][64 key][64] bf16, 16B-chunk swizzled: elem (r,d) at
//          col ((d>>3)^(r&7))*8 + (d&7)
// v_tiled: [20][32][64 dv][64 key] f16, 8B-granule swizzled: elem (dv,k) at
//          col (((k>>2)^(dv&15))<<2) + (k&3)
__global__ __launch_bounds__(256) void cape_split_kernel(
    const float* __restrict__ qkv, const float* __restrict__ p_out,
    const float* __restrict__ p_inv, short* __restrict__ qb,
    short* __restrict__ k_tiled, _Float16* __restrict__ v_tiled) {
  int idx = blockIdx.x * 256 + threadIdx.x;  // s*320 + g, grid exact
  int s = idx / 320;
  int g = idx - s * 320;
  int t = s >> 10;
  const float* Pq = p_inv + t * 16;
  const float* Pk = p_out + t * 16;
  const float4v* row = (const float4v*)(qkv + (size_t)s * 3840 + g * 4);
  float4v qv = row[0], kv = row[320], vv = row[640];
  int h = g >> 4;
  int dvb = (g & 15) * 4;
  const float QSCALE = 0.125f * 1.44269504f;  // hd^-0.5 * log2(e)
  short4v qo, ko;
#pragma unroll
  for (int j = 0; j < 4; j++) {
    float aq = 0.f, ak = 0.f;
#pragma unroll
    for (int k2 = 0; k2 < 4; k2++) {
      aq += qv[k2] * Pq[k2 * 4 + j];
      ak += kv[k2] * Pk[k2 * 4 + j];
    }
    qo[j] = f2bf(aq * QSCALE);
    ko[j] = f2bf(ak);
  }
  *(short4v*)(qb + ((size_t)h * 2048 + s) * 64 + dvb) = qo;
  // K: tile-major + chunk swizzle
  int kt = s >> 6, r = s & 63;
  int kcol = (((dvb >> 3) ^ (r & 7)) << 3) | (dvb & 7);
  *(short4v*)(k_tiled + (((size_t)h * 32 + kt) * 64 + r) * 64 + kcol) = ko;
  // V: tile-major [dv][key] + granule swizzle
  int kk = s & 63;
#pragma unroll
  for (int j = 0; j < 4; j++) {
    int dv = dvb + j;
    int vcol = ((((kk >> 2) ^ (dv & 15)) << 2)) | (kk & 3);
    v_tiled[(((size_t)h * 32 + kt) * 64 + dv) * 64 + vcol] = (_Float16)vv[j];
  }
}

// ---------------- flash attention: LDS-staged K/V, register P ----------------
// qb [20][2048][64] bf16, k_tiled/v_tiled as above, attn_out bf16 [2048][1280]
__global__ __launch_bounds__(256) void attn_kernel(
    const short* __restrict__ qb, const short* __restrict__ k_tiled,
    const _Float16* __restrict__ v_tiled, short* __restrict__ attn_out) {
  const int S = 2048, HD = 64;
  int h = blockIdx.x;
  int qblk = blockIdx.y;
  int tid = threadIdx.x;
  int w = tid >> 6, l = tid & 63;
  int lr = l & 15, lg = l >> 4;
  int q0 = qblk * 64 + w * 16;

  __shared__ __align__(16) short Kl[2][64][64];
  __shared__ __align__(16) _Float16 Vl[2][64][64];

  const short* qptr = qb + ((size_t)h * S + q0 + lr) * HD;
  short8 qf0 = *(const short8*)(qptr + lg * 8);
  short8 qf1 = *(const short8*)(qptr + 32 + lg * 8);

  auto stageKV = [&](int b, int kt) {
    const short* gk = k_tiled + (((size_t)h * 32 + kt) << 12) + tid * 8;
    const _Float16* gv = v_tiled + (((size_t)h * 32 + kt) << 12) + tid * 8;
    char* lk = (char*)&Kl[b][0][0] + w * 1024;
    char* lv = (char*)&Vl[b][0][0] + w * 1024;
    async16(lk, gk);
    async16(lk + 4096, gk + 2048);
    async16(lv, gv);
    async16(lv + 4096, gv + 2048);
  };

  float m = -1e30f, lsum = 0.f;
  f32x4 oacc[4] = {};  // O[q=lg*4+i][dv=nb*16+lr]

  auto compute_tile = [&](int buf) {
    const short* Kb = &Kl[buf][0][0];
    const _Float16* Vb = &Vl[buf][0][0];
    f32x4 st[4];
#pragma unroll
    for (int kk = 0; kk < 4; kk++) {
      int r = kk * 16 + lr;
      int sw = r & 7;
      short8 kf0 = *(const short8*)(Kb + r * 64 + ((lg ^ sw) << 3));
      short8 kf1 = *(const short8*)(Kb + r * 64 + (((4 + lg) ^ sw) << 3));
      f32x4 s0 = {};
      s0 = mfma16(kf0, qf0, s0);
      s0 = mfma16(kf1, qf1, s0);
      st[kk] = s0;
    }
    // online softmax in exp2 domain (q pre-scaled)
    float m0 = fmaxf(fmaxf(st[0][0], st[0][1]), fmaxf(st[0][2], st[0][3]));
    float m1 = fmaxf(fmaxf(st[1][0], st[1][1]), fmaxf(st[1][2], st[1][3]));
    float m2 = fmaxf(fmaxf(st[2][0], st[2][1]), fmaxf(st[2][2], st[2][3]));
    float m3 = fmaxf(fmaxf(st[3][0], st[3][1]), fmaxf(st[3][2], st[3][3]));
    float tm = fmaxf(fmaxf(m0, m1), fmaxf(m2, m3));
    tm = fmaxf(tm, __shfl_xor(tm, 16));
    tm = fmaxf(tm, __shfl_xor(tm, 32));
    if (!__all(tm <= m + 8.0f)) {  // defer-rescale (T13)
      float mnew = fmaxf(m, tm);
      float fac = __builtin_amdgcn_exp2f(m - mnew);
      lsum *= fac;
#pragma unroll
      for (int i = 0; i < 4; i++) {
        float fi = __shfl(fac, lg * 4 + i);
#pragma unroll
        for (int nb = 0; nb < 4; nb++) oacc[nb][i] *= fi;
      }
      m = mnew;
    }
    half4 pf[4];
    float ps[4];
#pragma unroll
    for (int kk = 0; kk < 4; kk++) {
      float p0 = __builtin_amdgcn_exp2f(st[kk][0] - m);
      float p1 = __builtin_amdgcn_exp2f(st[kk][1] - m);
      float p2 = __builtin_amdgcn_exp2f(st[kk][2] - m);
      float p3 = __builtin_amdgcn_exp2f(st[kk][3] - m);
      pf[kk][0] = (_Float16)p0;
      pf[kk][1] = (_Float16)p1;
      pf[kk][2] = (_Float16)p2;
      pf[kk][3] = (_Float16)p3;
      ps[kk] = (p0 + p1) + (p2 + p3);
    }
    float psum = (ps[0] + ps[1]) + (ps[2] + ps[3]);
    psum += __shfl_xor(psum, 16);
    psum += __shfl_xor(psum, 32);
    lsum += psum;
    // PV: register P (A-frag), V from LDS (B-frag), K=16 f16 MFMA
#pragma unroll
    for (int kk = 0; kk < 4; kk++) {
      half4 vf[4];
#pragma unroll
      for (int nb = 0; nb < 4; nb++) {
        int dv = nb * 16 + lr;
        vf[nb] = *(const half4*)(Vb + dv * 64 + ((((kk << 2) + lg) ^ lr) << 2));
      }
#pragma unroll
      for (int nb = 0; nb < 4; nb++)
        oacc[nb] = __builtin_amdgcn_mfma_f32_16x16x16f16(pf[kk], vf[nb], oacc[nb], 0, 0, 0);
    }
  };

  stageKV(0, 0);
  for (int kt2 = 0; kt2 < 32; kt2 += 2) {
    __syncthreads();
    if (kt2 + 1 < 32) stageKV(1, kt2 + 1);
    compute_tile(0);
    __syncthreads();
    if (kt2 + 2 < 32) stageKV(0, kt2 + 2);
    compute_tile(1);
  }

#pragma unroll
  for (int i = 0; i < 4; i++) {
    float li = __shfl(lsum, lg * 4 + i);
    float inv = 1.0f / li;
    int row = q0 + lg * 4 + i;
#pragma unroll
    for (int nb = 0; nb < 4; nb++)
      attn_out[(size_t)row * 1280 + h * 64 + nb * 16 + lr] = f2bf(oacc[nb][i] * inv);
  }
}

// ---------------- launch ----------------

extern "C" void kernel_launch(void* const* d_in, const int* in_sizes, int n_in,
                              void* d_out, int out_size, void* d_ws, size_t ws_size,
                              hipStream_t stream) {
  const float* hs = (const float*)d_in[0];
  const float* p_out = (const float*)d_in[1];
  const float* p_inv = (const float*)d_in[2];
  const float* Wq = (const float*)d_in[3];
  const float* Wk = (const float*)d_in[4];
  const float* Wv = (const float*)d_in[5];
  const float* Wo = (const float*)d_in[6];
  const float* bo = (const float*)d_in[7];
  float* out = (float*)d_out;
  char* ws = (char*)d_ws;

  // workspace layout
  short* hs_bf = (short*)(ws + 0);              // 5,242,880
  short* wqkv_t = (short*)(ws + 5242880);       // 9,830,400
  short* wo_t = (short*)(ws + 15073280);        // 3,276,800
  float* qkv = (float*)(ws + 18350080);         // 31,457,280
  short* q_bf = (short*)(ws + 49807360);        // 5,242,880
  short* k_tiled = (short*)(ws + 55050240);     // 5,242,880
  _Float16* v_tiled = (_Float16*)(ws + 60293120); // 5,242,880 (ends 65,536,000)
  short* attn_bf = (short*)(ws + 18350080);     // reuse qkv region

  const int n_hs = 2048 * 1280;
  cvt_bf16_kernel<<<(n_hs + 255) / 256, 256, 0, stream>>>(hs, hs_bf, n_hs);

  dim3 tb(32, 8);
  transpose_cvt_kernel<<<dim3(40, 40), tb, 0, stream>>>(Wq, wqkv_t, 1280, 1280);
  transpose_cvt_kernel<<<dim3(40, 40), tb, 0, stream>>>(Wk, wqkv_t + (size_t)1280 * 1280, 1280, 1280);
  transpose_cvt_kernel<<<dim3(40, 40), tb, 0, stream>>>(Wv, wqkv_t + (size_t)2560 * 1280, 1280, 1280);
  transpose_cvt_kernel<<<dim3(40, 40), tb, 0, stream>>>(Wo, wo_t, 1280, 1280);

  // QKV: [2048][1280] @ [1280][3840]^T' -> [2048][3840] f32
  gemm128_kernel<0><<<dim3(30, 16), 256, 0, stream>>>(
      hs_bf, wqkv_t, 2048, 3840, 1280, qkv, nullptr, nullptr, nullptr);

  cape_split_kernel<<<2560, 256, 0, stream>>>(qkv, p_out, p_inv, q_bf, k_tiled, v_tiled);

  attn_kernel<<<dim3(20, 32), 256, 0, stream>>>(q_bf, k_tiled, v_tiled, attn_bf);

  // out = attn @ Wo + bo + residual
  gemm128_kernel<1><<<dim3(10, 16), 256, 0, stream>>>(
      attn_bf, wo_t, 2048, 1280, 1280, nullptr, bo, hs, out);
}

// Round 4
// 141.296 us; speedup vs baseline: 3.5118x; 1.0822x over previous
//
#include <hip/hip_runtime.h>

typedef short short8 __attribute__((ext_vector_type(8)));
typedef short short4v __attribute__((ext_vector_type(4)));
typedef float f32x4 __attribute__((ext_vector_type(4)));
typedef __bf16 bf16x8 __attribute__((ext_vector_type(8)));
typedef _Float16 half4 __attribute__((ext_vector_type(4)));

__device__ __forceinline__ short f2bf(float x) {
  unsigned u = __builtin_bit_cast(unsigned, x);
  u += 0x7fffu + ((u >> 16) & 1u);   // round-to-nearest-even
  return (short)(u >> 16);
}

__device__ __forceinline__ f32x4 mfma16(short8 a, short8 b, f32x4 c) {
  return __builtin_amdgcn_mfma_f32_16x16x32_bf16(
      __builtin_bit_cast(bf16x8, a), __builtin_bit_cast(bf16x8, b), c, 0, 0, 0);
}

// async global->LDS, 16B per lane; lds is wave-uniform base (lane i writes base+i*16)
__device__ __forceinline__ void async16(void* lds, const void* g) {
  __builtin_amdgcn_global_load_lds(
      (const __attribute__((address_space(1))) unsigned*)g,
      (__attribute__((address_space(3))) unsigned*)lds, 16, 0, 0);
}

// ---------------- conversion ----------------

__global__ __launch_bounds__(256) void cvt_bf16_kernel(
    const float* __restrict__ x, short* __restrict__ y, int n) {
  int i = blockIdx.x * 256 + threadIdx.x;
  if (i < n) y[i] = f2bf(x[i]);
}

// W: [1280][1280] f32 row-major -> BT[n][k] bf16 with optional fused CAPE:
// BT_t[n][k] = scale * sum_j W[k][(n&~3)+j] * P[t][j][n&3]   (P: [2][4][4])
// P==null: plain transpose*scale (dst1 gets a copy if non-null).
__global__ __launch_bounds__(256) void capeT_kernel(
    const float* __restrict__ W, const float* __restrict__ P, float scale,
    short* __restrict__ dst0, short* __restrict__ dst1) {
  __shared__ float tile[32][33];
  const int ND = 1280, KD = 1280;
  int bn = blockIdx.x * 32, bk = blockIdx.y * 32;
  int tx = threadIdx.x, ty = threadIdx.y;  // 32 x 8
  for (int i = ty; i < 32; i += 8)
    tile[i][tx] = W[(size_t)(bk + i) * ND + bn + tx];
  __syncthreads();
  for (int c = ty; c < 32; c += 8) {
    float v0, v1;
    if (P) {
      int g = c & ~3, jj = c & 3;
      float a0 = 0.f, a1 = 0.f;
#pragma unroll
      for (int j = 0; j < 4; j++) {
        float wv = tile[tx][g + j];
        a0 += wv * P[j * 4 + jj];
        a1 += wv * P[16 + j * 4 + jj];
      }
      v0 = a0 * scale;
      v1 = a1 * scale;
    } else {
      v0 = v1 = tile[tx][c] * scale;
    }
    size_t o = (size_t)(bn + c) * KD + bk + tx;
    dst0[o] = f2bf(v0);
    if (dst1) dst1[o] = f2bf(v1);
  }
}

// ---------------- GEMM (m97 structure): C = A[M,K] @ BT[N,K]^T ----------
// 128x128 tile, BK=32, double-buffered LDS via global_load_lds.
// B matrix selected per M-block: rows >=1024 use B1 (CAPE t=1), else B0.
// EPI=1: out = acc + bias[col] + resid (f32).  EPI=2: scatter to attention
// layouts (q rows / swizzled k_tiled / swizzled v_tiled), col section-uniform
// per block (N sections of 1280, blocks 128-wide).

template <int EPI>
__global__ __launch_bounds__(256) void gemm128_kernel(
    const short* __restrict__ A, const short* __restrict__ B0,
    const short* __restrict__ B1, int M, int N, int K,
    const float* __restrict__ bias, const float* __restrict__ resid,
    float* __restrict__ out, short* __restrict__ qb,
    short* __restrict__ ktl, _Float16* __restrict__ vtl) {
  __shared__ __align__(16) short As[2][128][32];
  __shared__ __align__(16) short Bs[2][128][32];
  int tid = threadIdx.x;
  int l = tid & 63, w = tid >> 6;
  int wr = w >> 1, wc = w & 1;
  int lr = l & 15, lg = l >> 4;
  int bm = blockIdx.y * 128, bn = blockIdx.x * 128;
  const short* BT = (bm >= 1024) ? B1 : B0;
  f32x4 acc[4][4] = {};

  auto stage = [&](int b, int k0) {
    const short* ga = A + (size_t)(bm + (tid >> 2)) * K + k0 + (tid & 3) * 8;
    const short* gb = BT + (size_t)(bn + (tid >> 2)) * K + k0 + (tid & 3) * 8;
    char* la = (char*)&As[b][0][0] + w * 1024;
    char* lb = (char*)&Bs[b][0][0] + w * 1024;
    async16(la, ga);
    async16(la + 4096, ga + (size_t)64 * K);
    async16(lb, gb);
    async16(lb + 4096, gb + (size_t)64 * K);
  };

  auto compute = [&](int b) {
    const short* Ab = &As[b][0][0];
    const short* Bb = &Bs[b][0][0];
    short8 af[4], bf_[4];
#pragma unroll
    for (int mi = 0; mi < 4; mi++)
      af[mi] = *(const short8*)(Ab + (wr * 64 + mi * 16 + lr) * 32 + lg * 8);
#pragma unroll
    for (int nj = 0; nj < 4; nj++)
      bf_[nj] = *(const short8*)(Bb + (wc * 64 + nj * 16 + lr) * 32 + lg * 8);
#pragma unroll
    for (int mi = 0; mi < 4; mi++)
#pragma unroll
      for (int nj = 0; nj < 4; nj++)
        acc[mi][nj] = mfma16(af[mi], bf_[nj], acc[mi][nj]);
  };

  int nk = K >> 5;
  stage(0, 0);
  for (int ks = 0; ks < nk; ks += 2) {
    __syncthreads();
    if (ks + 1 < nk) stage(1, (ks + 1) << 5);
    compute(0);
    __syncthreads();
    if (ks + 2 < nk) stage(0, (ks + 2) << 5);
    compute(1);
  }

#pragma unroll
  for (int mi = 0; mi < 4; mi++)
#pragma unroll
    for (int nj = 0; nj < 4; nj++)
#pragma unroll
      for (int i = 0; i < 4; i++) {
        int row = bm + wr * 64 + mi * 16 + lg * 4 + i;
        int col = bn + wc * 64 + nj * 16 + lr;
        float v = acc[mi][nj][i];
        if (EPI == 1) {
          out[(size_t)row * N + col] = v + bias[col] + resid[(size_t)row * N + col];
        } else {
          int s = row;
          if (col < 1280) {                       // Q: [20][2048][64] rows
            qb[(((size_t)(col >> 6)) * 2048 + s) * 64 + (col & 63)] = f2bf(v);
          } else if (col < 2560) {                // K: tiled + 16B-chunk swizzle
            int cc = col - 1280;
            int h = cc >> 6, d = cc & 63;
            int kt = s >> 6, r = s & 63;
            int kcol = (((d >> 3) ^ (r & 7)) << 3) | (d & 7);
            ktl[(((size_t)h * 32 + kt) * 64 + r) * 64 + kcol] = f2bf(v);
          } else {                                // V: [dv][key] tiled + swizzle
            int cc = col - 2560;
            int h = cc >> 6, dv = cc & 63;
            int kt = s >> 6, kk = s & 63;
            int vcol = (((kk >> 2) ^ (dv & 15)) << 2) | (kk & 3);
            vtl[(((size_t)h * 32 + kt) * 64 + dv) * 64 + vcol] = (_Float16)v;
          }
        }
      }
}

// ---------------- flash attention: LDS-staged K/V, register P ----------------
__global__ __launch_bounds__(256) void attn_kernel(
    const short* __restrict__ qb, const short* __restrict__ k_tiled,
    const _Float16* __restrict__ v_tiled, short* __restrict__ attn_out) {
  const int S = 2048, HD = 64;
  int h = blockIdx.x;
  int qblk = blockIdx.y;
  int tid = threadIdx.x;
  int w = tid >> 6, l = tid & 63;
  int lr = l & 15, lg = l >> 4;
  int q0 = qblk * 64 + w * 16;

  __shared__ __align__(16) short Kl[2][64][64];
  __shared__ __align__(16) _Float16 Vl[2][64][64];

  const short* qptr = qb + ((size_t)h * S + q0 + lr) * HD;
  short8 qf0 = *(const short8*)(qptr + lg * 8);
  short8 qf1 = *(const short8*)(qptr + 32 + lg * 8);

  auto stageKV = [&](int b, int kt) {
    const short* gk = k_tiled + (((size_t)h * 32 + kt) << 12) + tid * 8;
    const _Float16* gv = v_tiled + (((size_t)h * 32 + kt) << 12) + tid * 8;
    char* lk = (char*)&Kl[b][0][0] + w * 1024;
    char* lv = (char*)&Vl[b][0][0] + w * 1024;
    async16(lk, gk);
    async16(lk + 4096, gk + 2048);
    async16(lv, gv);
    async16(lv + 4096, gv + 2048);
  };

  float m = -1e30f, lsum = 0.f;
  f32x4 oacc[4] = {};  // O[q=lg*4+i][dv=nb*16+lr]

  auto compute_tile = [&](int buf) {
    const short* Kb = &Kl[buf][0][0];
    const _Float16* Vb = &Vl[buf][0][0];
    f32x4 st[4];
#pragma unroll
    for (int kk = 0; kk < 4; kk++) {
      int r = kk * 16 + lr;
      int sw = r & 7;
      short8 kf0 = *(const short8*)(Kb + r * 64 + ((lg ^ sw) << 3));
      short8 kf1 = *(const short8*)(Kb + r * 64 + (((4 + lg) ^ sw) << 3));
      f32x4 s0 = {};
      s0 = mfma16(kf0, qf0, s0);
      s0 = mfma16(kf1, qf1, s0);
      st[kk] = s0;
    }
    float m0 = fmaxf(fmaxf(st[0][0], st[0][1]), fmaxf(st[0][2], st[0][3]));
    float m1 = fmaxf(fmaxf(st[1][0], st[1][1]), fmaxf(st[1][2], st[1][3]));
    float m2 = fmaxf(fmaxf(st[2][0], st[2][1]), fmaxf(st[2][2], st[2][3]));
    float m3 = fmaxf(fmaxf(st[3][0], st[3][1]), fmaxf(st[3][2], st[3][3]));
    float tm = fmaxf(fmaxf(m0, m1), fmaxf(m2, m3));
    tm = fmaxf(tm, __shfl_xor(tm, 16));
    tm = fmaxf(tm, __shfl_xor(tm, 32));
    if (!__all(tm <= m + 8.0f)) {  // defer-rescale (T13)
      float mnew = fmaxf(m, tm);
      float fac = __builtin_amdgcn_exp2f(m - mnew);
      lsum *= fac;
#pragma unroll
      for (int i = 0; i < 4; i++) {
        float fi = __shfl(fac, lg * 4 + i);
#pragma unroll
        for (int nb = 0; nb < 4; nb++) oacc[nb][i] *= fi;
      }
      m = mnew;
    }
    half4 pf[4];
    float ps[4];
#pragma unroll
    for (int kk = 0; kk < 4; kk++) {
      float p0 = __builtin_amdgcn_exp2f(st[kk][0] - m);
      float p1 = __builtin_amdgcn_exp2f(st[kk][1] - m);
      float p2 = __builtin_amdgcn_exp2f(st[kk][2] - m);
      float p3 = __builtin_amdgcn_exp2f(st[kk][3] - m);
      pf[kk][0] = (_Float16)p0;
      pf[kk][1] = (_Float16)p1;
      pf[kk][2] = (_Float16)p2;
      pf[kk][3] = (_Float16)p3;
      ps[kk] = (p0 + p1) + (p2 + p3);
    }
    float psum = (ps[0] + ps[1]) + (ps[2] + ps[3]);
    psum += __shfl_xor(psum, 16);
    psum += __shfl_xor(psum, 32);
    lsum += psum;
#pragma unroll
    for (int kk = 0; kk < 4; kk++) {
      half4 vf[4];
#pragma unroll
      for (int nb = 0; nb < 4; nb++) {
        int dv = nb * 16 + lr;
        vf[nb] = *(const half4*)(Vb + dv * 64 + ((((kk << 2) + lg) ^ lr) << 2));
      }
#pragma unroll
      for (int nb = 0; nb < 4; nb++)
        oacc[nb] = __builtin_amdgcn_mfma_f32_16x16x16f16(pf[kk], vf[nb], oacc[nb], 0, 0, 0);
    }
  };

  stageKV(0, 0);
  for (int kt2 = 0; kt2 < 32; kt2 += 2) {
    __syncthreads();
    if (kt2 + 1 < 32) stageKV(1, kt2 + 1);
    compute_tile(0);
    __syncthreads();
    if (kt2 + 2 < 32) stageKV(0, kt2 + 2);
    compute_tile(1);
  }

#pragma unroll
  for (int i = 0; i < 4; i++) {
    float li = __shfl(lsum, lg * 4 + i);
    float inv = 1.0f / li;
    int row = q0 + lg * 4 + i;
#pragma unroll
    for (int nb = 0; nb < 4; nb++)
      attn_out[(size_t)row * 1280 + h * 64 + nb * 16 + lr] = f2bf(oacc[nb][i] * inv);
  }
}

// ---------------- launch ----------------

extern "C" void kernel_launch(void* const* d_in, const int* in_sizes, int n_in,
                              void* d_out, int out_size, void* d_ws, size_t ws_size,
                              hipStream_t stream) {
  const float* hs = (const float*)d_in[0];
  const float* p_out = (const float*)d_in[1];
  const float* p_inv = (const float*)d_in[2];
  const float* Wq = (const float*)d_in[3];
  const float* Wk = (const float*)d_in[4];
  const float* Wv = (const float*)d_in[5];
  const float* Wo = (const float*)d_in[6];
  const float* bo = (const float*)d_in[7];
  float* out = (float*)d_out;
  char* ws = (char*)d_ws;

  // workspace layout (bytes)
  short* hs_bf = (short*)(ws + 0);                  //  5,242,880
  short* BT0 = (short*)(ws + 5242880);              //  9,830,400  [3840][1280] t=0
  short* BT1 = (short*)(ws + 15073280);             //  9,830,400  [3840][1280] t=1
  short* wo_t = (short*)(ws + 24903680);            //  3,276,800
  short* q_bf = (short*)(ws + 28180480);            //  5,242,880
  short* k_tiled = (short*)(ws + 33423360);         //  5,242,880
  _Float16* v_tiled = (_Float16*)(ws + 38666240);   //  5,242,880
  short* attn_bf = (short*)(ws + 43909120);         //  5,242,880 (ends 49,152,000)

  const float QSCALE = 0.125f * 1.44269504f;  // hd^-0.5 * log2(e)
  const int n_hs = 2048 * 1280;
  cvt_bf16_kernel<<<(n_hs + 255) / 256, 256, 0, stream>>>(hs, hs_bf, n_hs);

  dim3 tb(32, 8), tg(40, 40);
  // Q weights: fold CAPE p_inv + softmax scale + log2e
  capeT_kernel<<<tg, tb, 0, stream>>>(Wq, p_inv, QSCALE, BT0, BT1);
  // K weights: fold CAPE p_out
  capeT_kernel<<<tg, tb, 0, stream>>>(Wk, p_out, 1.0f,
                                      BT0 + (size_t)1280 * 1280, BT1 + (size_t)1280 * 1280);
  // V weights: plain transpose, both t copies
  capeT_kernel<<<tg, tb, 0, stream>>>(Wv, nullptr, 1.0f,
                                      BT0 + (size_t)2560 * 1280, BT1 + (size_t)2560 * 1280);
  // O weights: plain transpose
  capeT_kernel<<<tg, tb, 0, stream>>>(Wo, nullptr, 1.0f, wo_t, nullptr);

  // QKV GEMM with fused CAPE (in weights) + scatter epilogue to attn layouts
  gemm128_kernel<2><<<dim3(30, 16), 256, 0, stream>>>(
      hs_bf, BT0, BT1, 2048, 3840, 1280,
      nullptr, nullptr, nullptr, q_bf, k_tiled, v_tiled);

  attn_kernel<<<dim3(20, 32), 256, 0, stream>>>(q_bf, k_tiled, v_tiled, attn_bf);

  // out = attn @ Wo + bo + residual
  gemm128_kernel<1><<<dim3(10, 16), 256, 0, stream>>>(
      attn_bf, wo_t, wo_t, 2048, 1280, 1280,
      bo, hs, out, nullptr, nullptr, nullptr);
}